// Round 2
// baseline (172.104 us; speedup 1.0000x reference)
//
#include <hip/hip_runtime.h>
#include <math.h>

// VectorQuantizer on MI355X — R12: R11 with the compile fix (nontemporal store
// requires a clang ext-vector type, not HIP's float4 class).
// R11 theory: top-5 = harness 256 MiB ws-poison fills (43 µs, untouchable);
// both our kernels under the 42.2 µs cutoff. Removable overhead: the 1-block
// vq_final_p (single-CU 1 MB pull ~8-12 µs + graph launch gap). Fuse via a
// device-scope done-counter cascade — the 16 last-finishing blocks each reduce
// 32 pcounts rows in parallel, the last of those combines + writes
// loss/perplexity. Also: B3 barrier dropped (hist is per-wave over wave-local
// idxbuf; sred/hist reads still covered by B4) and `out` stores nontemporal
// (33.5 MB write-once stream; keep L2 for the hot codebook).
// Count sums are integer-valued fp32 (< 2^24, exact under reorder); ssep
// double tree is order-identical to R10 -> results bit-identical.
// ws: [0,1MB) partials f32[512][512] | [1MB,+4K) ssep f64[512]
//     | [+36K) part2 f32[16][512] starts at 1MB+4K | [1MB+36K,+8B) ctrs u32[2]

#define NTOK 131072
#define KCODES 512
#define HW 4096
#define CHW 262144
#define NELEM 8388608

typedef __attribute__((ext_vector_type(8))) short short8;
typedef __attribute__((ext_vector_type(4))) float f32x4;

static __device__ __forceinline__ unsigned short f2bf(float f) {
    unsigned u = __float_as_uint(f);
    unsigned r = u + 0x7FFFu + ((u >> 16) & 1u);  // RNE
    return (unsigned short)(r >> 16);
}

__global__ __launch_bounds__(512, 4) void vq_main(const float* __restrict__ in,
                                                  const float* __restrict__ w,
                                                  float* __restrict__ out,
                                                  float* __restrict__ pcounts,
                                                  double* __restrict__ ssep,
                                                  float* __restrict__ part2,
                                                  unsigned* __restrict__ ctrs,
                                                  float* __restrict__ counts,
                                                  double* __restrict__ sse_acc,
                                                  const int amode) {
    __shared__ __align__(16) unsigned short wh[KCODES * 64];  // 65536 B bf16 W
    __shared__ float wsqp[KCODES];              // 2048 B: 1.25 + ||w_k||^2
    __shared__ int idxbuf[256];                 // 1024 B
    __shared__ int hist[KCODES];                // 2048 B block histogram
    __shared__ double sred[8];                  // per-wave sse partials
    __shared__ int role_sh;                     // done-counter broadcast

    const int tid = threadIdx.x;
    const int lane = tid & 63, wv = tid >> 6;   // wv in [0,8)
    const int col = lane & 15, quad = lane >> 4;
    const int ntok0 = blockIdx.x * 256;

    wsqp[tid] = 1.25f;
    hist[tid] = 0;
    __syncthreads();  // B1: wsqp/hist init before use

    // ---- interleaved: 1 W-staging chunk + 4 X gather dwords per iter (8) ----
    const float* gbase = in + (ntok0 >> 12) * CHW + (ntok0 & 4095) + wv * 32 + col;
    short8 ah[2][2];
    float xsq = 0.f;
#pragma unroll
    for (int it = 0; it < 8; ++it) {
        const int g = it * 512 + tid;
        const int cc = g & 15, qd = (g >> 4) & 3, ch = (g >> 6) & 1, tt = g >> 7;
        const float4* src = (const float4*)(w + (tt * 16 + cc) * 64 + ch * 32 + qd * 8);
        const float4 v0 = src[0], v1 = src[1];
        const int sub = it >> 2, c = (it >> 1) & 1, j0 = (it & 1) * 4;
        const float* gp = gbase + sub * 16 + (c * 32 + quad * 8 + j0) * HW;
        const float x0 = gp[0 * HW], x1 = gp[1 * HW], x2 = gp[2 * HW], x3 = gp[3 * HW];

        short8 hv;
        hv[0] = (short)f2bf(v0.x); hv[1] = (short)f2bf(v0.y);
        hv[2] = (short)f2bf(v0.z); hv[3] = (short)f2bf(v0.w);
        hv[4] = (short)f2bf(v1.x); hv[5] = (short)f2bf(v1.y);
        hv[6] = (short)f2bf(v1.z); hv[7] = (short)f2bf(v1.w);
        *(short8*)(wh + g * 8) = hv;
        float ws2 = v0.x * v0.x;
        ws2 = fmaf(v0.y, v0.y, ws2); ws2 = fmaf(v0.z, v0.z, ws2);
        ws2 = fmaf(v0.w, v0.w, ws2); ws2 = fmaf(v1.x, v1.x, ws2);
        ws2 = fmaf(v1.y, v1.y, ws2); ws2 = fmaf(v1.z, v1.z, ws2);
        ws2 = fmaf(v1.w, v1.w, ws2);
        atomicAdd(&wsqp[tt * 16 + cc], ws2);  // LDS atomic

        ah[sub][c][j0 + 0] = (short)f2bf(-2.0f * x0);
        ah[sub][c][j0 + 1] = (short)f2bf(-2.0f * x1);
        ah[sub][c][j0 + 2] = (short)f2bf(-2.0f * x2);
        ah[sub][c][j0 + 3] = (short)f2bf(-2.0f * x3);
        xsq = fmaf(x0, x0, xsq); xsq = fmaf(x1, x1, xsq);
        xsq = fmaf(x2, x2, xsq); xsq = fmaf(x3, x3, xsq);
    }
    __syncthreads();  // B2: wh + wsqp complete

    // ---- scan 32 tiles of 16 codes; key = (float_bits(d)<<9)|code ----
    unsigned runkey[2][4];
#pragma unroll
    for (int sub = 0; sub < 2; ++sub)
#pragma unroll
        for (int r = 0; r < 4; ++r) runkey[sub][r] = 0xFFFFFFFFu;

#pragma unroll 1
    for (int t = 0; t < 32; ++t) {
        const unsigned short* ph = wh + t * 1024 + quad * 128 + col * 8;
        const short8 b0 = *(const short8*)ph;
        const short8 b1 = *(const short8*)(ph + 512);
        const int code = t * 16 + col;
        const float seed = wsqp[code];
#pragma unroll
        for (int sub = 0; sub < 2; ++sub) {
            f32x4 acc = {seed, seed, seed, seed};
            acc = __builtin_amdgcn_mfma_f32_16x16x32_bf16(ah[sub][0], b0, acc, 0, 0, 0);
            acc = __builtin_amdgcn_mfma_f32_16x16x32_bf16(ah[sub][1], b1, acc, 0, 0, 0);
#pragma unroll
            for (int r = 0; r < 4; ++r) {
                const unsigned key = (__float_as_uint(acc[r]) << 9) | code;
                runkey[sub][r] = key < runkey[sub][r] ? key : runkey[sub][r];
            }
        }
    }

    // ---- cross-lane argmin over the 16 code-cols ----
#pragma unroll
    for (int s = 1; s < 16; s <<= 1)
#pragma unroll
        for (int sub = 0; sub < 2; ++sub)
#pragma unroll
            for (int r = 0; r < 4; ++r) {
                const unsigned o = __shfl_xor(runkey[sub][r], s, 64);
                runkey[sub][r] = o < runkey[sub][r] ? o : runkey[sub][r];
            }

    // d_best (exact from key) + publish indices (wave-local consumers only)
    float dsum = 0.f;
    if (col == 0) {
#pragma unroll
        for (int sub = 0; sub < 2; ++sub)
#pragma unroll
            for (int r = 0; r < 4; ++r) {
                const unsigned key = runkey[sub][r];
                idxbuf[wv * 32 + sub * 16 + quad * 4 + r] = (int)(key & 511u);
                dsum += __uint_as_float((key >> 9) | 0x3F800000u) - 1.25f;
            }
    }
    float contrib = xsq + dsum;
#pragma unroll
    for (int off = 32; off > 0; off >>= 1) contrib += __shfl_down(contrib, off, 64);
    if (lane == 0) sred[wv] = (double)contrib;

    // per-wave histogram: idxbuf[wv*32+..] was written by THIS wave (col==0
    // lanes); wave-synchronous LDS RAW needs only compiler lgkmcnt — no B3.
    if (lane < 32) atomicAdd(&hist[idxbuf[wv * 32 + lane]], 1);

    // ---- epilogue: write w rows only (L2-hot); 4 lanes/token, 2 passes ----
    // out is a 33.5 MB write-once stream -> nontemporal, keep L2 for W.
#pragma unroll
    for (int p = 0; p < 2; ++p) {
        const int tl = p * 16 + (lane >> 2), q = lane & 3;
        const int n = ntok0 + wv * 32 + tl;
        const int bidx = idxbuf[wv * 32 + tl];
        const f32x4* wr = (const f32x4*)(w + bidx * 64 + q * 16);
        f32x4* op = (f32x4*)(out + n * 64 + q * 16);
#pragma unroll
        for (int i = 0; i < 4; ++i) {
            const f32x4 v = wr[i];
            __builtin_nontemporal_store(v, op + i);
        }
    }
    __syncthreads();  // B4: hist + sred complete

    if (!amode) {
        pcounts[(blockIdx.x << 9) + tid] = (float)hist[tid];  // plain store
        if (tid == 0) {
            double s = sred[0];
#pragma unroll
            for (int i = 1; i < 8; ++i) s += sred[i];
            ssep[blockIdx.x] = s;
        }
        __syncthreads();  // B5: all global stores issued (vmcnt drained)
        if (tid == 0) {
            __threadfence();                       // release: wb local L2
            role_sh = (int)atomicAdd(ctrs, 1u);    // device-scope
        }
        __syncthreads();  // B6: broadcast role
        const int old = role_sh;

        if (old >= 512 - 16) {  // one of the 16 last finishers -> reducer
            const int r = old - (512 - 16);
            if (tid == 0) {
                while (__hip_atomic_load(ctrs, __ATOMIC_RELAXED,
                                         __HIP_MEMORY_SCOPE_AGENT) < 512u)
                    __builtin_amdgcn_s_sleep(2);
            }
            __syncthreads();
            __threadfence();  // acquire: invalidate local caches

            // sum 32 pcounts rows for all 512 codes (coalesced across tid)
            const float* pc = pcounts + (r << 14) + tid;
            float s = 0.f;
#pragma unroll
            for (int b = 0; b < 32; ++b) s += pc[b << 9];  // integers: exact
            part2[(r << 9) + tid] = s;
            __syncthreads();  // drain partial stores
            if (tid == 0) {
                __threadfence();
                role_sh = (int)atomicAdd(ctrs + 1, 1u);
            }
            __syncthreads();

            if (role_sh == 15) {  // last reducer -> combiner (no spin needed)
                __threadfence();
                // wh is dead past the scan: reuse as double scratch
                double* const dred = (double*)wh;
                double* const dsred = dred + KCODES;
                float cnt = 0.f;
#pragma unroll
                for (int rr = 0; rr < 16; ++rr) cnt += part2[(rr << 9) + tid];
                const double p = (double)cnt / (double)NTOK;
                dred[tid] = p * log(p + 1e-10);
                dsred[tid] = ssep[tid];
                __syncthreads();
#pragma unroll
                for (int st = 256; st > 0; st >>= 1) {
                    if (tid < st) {
                        dred[tid] += dred[tid + st];
                        dsred[tid] += dsred[tid + st];
                    }
                    __syncthreads();
                }
                if (tid == 0) {
                    out[NELEM] = (float)((dsred[0] / (double)NELEM) * 1.25);
                    out[NELEM + 1] = (float)exp(-dred[0]);
                }
            }
        }
    } else {  // fallback: ws too small for partials/counters
        const int h = hist[tid];
        if (h) atomicAdd(&counts[tid], (float)h);
        if (tid == 0) {
            double s = sred[0];
#pragma unroll
            for (int i = 1; i < 8; ++i) s += sred[i];
            atomicAdd(sse_acc, s);
        }
    }
}

__global__ __launch_bounds__(512) void vq_final_a(const float* __restrict__ counts,
                                                  const double* __restrict__ sse_acc,
                                                  float* __restrict__ out) {
    __shared__ double red[512];
    const int k = threadIdx.x;
    const double p = (double)counts[k] / (double)NTOK;
    red[k] = p * log(p + 1e-10);
    __syncthreads();
#pragma unroll
    for (int st = 256; st > 0; st >>= 1) {
        if (k < st) red[k] += red[k + st];
        __syncthreads();
    }
    if (k == 0) {
        out[NELEM] = (float)((*sse_acc / (double)NELEM) * 1.25);
        out[NELEM + 1] = (float)exp(-red[0]);
    }
}

extern "C" void kernel_launch(void* const* d_in, const int* in_sizes, int n_in,
                              void* d_out, int out_size, void* d_ws, size_t ws_size,
                              hipStream_t stream) {
    const float* in = (const float*)d_in[0];
    const float* w = (const float*)d_in[1];
    float* out = (float*)d_out;
    char* ws = (char*)d_ws;

    const size_t PC = 0;
    const size_t SS = (size_t)1 << 20;            // 1 MB
    const size_t P2 = SS + 4096;                  // +4 KB
    const size_t CT = P2 + 32768;                 // +32 KB
    const size_t need = CT + 8;
    if (ws_size >= need) {
        float* pcounts = (float*)(ws + PC);
        double* ssep = (double*)(ws + SS);
        float* part2 = (float*)(ws + P2);
        unsigned* ctrs = (unsigned*)(ws + CT);
        (void)hipMemsetAsync(ctrs, 0, 8, stream); // zero done-counters (8 B)
        vq_main<<<512, 512, 0, stream>>>(in, w, out, pcounts, ssep, part2, ctrs,
                                         nullptr, nullptr, 0);
    } else {  // fallback: R6-style atomics
        float* counts = (float*)ws;
        double* sse_acc = (double*)(ws + 2048);
        (void)hipMemsetAsync(ws, 0, 2056, stream);
        vq_main<<<512, 512, 0, stream>>>(in, w, out, nullptr, nullptr, nullptr,
                                         nullptr, counts, sse_acc, 1);
        vq_final_a<<<1, 512, 0, stream>>>(counts, sse_acc, out);
    }
}

// Round 3
// 140.508 us; speedup vs baseline: 1.2249x; 1.2249x over previous
//
#include <hip/hip_runtime.h>
#include <math.h>

// VectorQuantizer on MI355X — R13: R12 minus nontemporal stores.
// R12 post-mortem: fused cascade was correct but vq_main went 40->106 µs.
// WRITE_SIZE showed 78 MB vs ~36 MB ideal: nontemporal 16B stores at 64B
// stride bypass L2 write-combining -> partial-sector HBM writes (~2.3x
// amplification, consistent with 32B granule) -> ~50 µs of extra write cost.
// Revert epilogue to plain cached float4 stores (R10 pattern); keep the
// done-counter cascade (16 last blocks reduce pcounts, last combines) which
// replaces the 1-block vq_final_p dispatch + its launch gap.
// Count sums are integer-valued fp32 (< 2^24, exact under reorder); ssep
// double tree is order-identical to R10 -> results bit-identical.
// ws: [0,1MB) partials f32[512][512] | [1MB,+4K) ssep f64[512]
//     | [+36K) part2 f32[16][512] starts at 1MB+4K | [1MB+36K,+8B) ctrs u32[2]

#define NTOK 131072
#define KCODES 512
#define HW 4096
#define CHW 262144
#define NELEM 8388608

typedef __attribute__((ext_vector_type(8))) short short8;
typedef __attribute__((ext_vector_type(4))) float f32x4;

static __device__ __forceinline__ unsigned short f2bf(float f) {
    unsigned u = __float_as_uint(f);
    unsigned r = u + 0x7FFFu + ((u >> 16) & 1u);  // RNE
    return (unsigned short)(r >> 16);
}

__global__ __launch_bounds__(512, 4) void vq_main(const float* __restrict__ in,
                                                  const float* __restrict__ w,
                                                  float* __restrict__ out,
                                                  float* __restrict__ pcounts,
                                                  double* __restrict__ ssep,
                                                  float* __restrict__ part2,
                                                  unsigned* __restrict__ ctrs,
                                                  float* __restrict__ counts,
                                                  double* __restrict__ sse_acc,
                                                  const int amode) {
    __shared__ __align__(16) unsigned short wh[KCODES * 64];  // 65536 B bf16 W
    __shared__ float wsqp[KCODES];              // 2048 B: 1.25 + ||w_k||^2
    __shared__ int idxbuf[256];                 // 1024 B
    __shared__ int hist[KCODES];                // 2048 B block histogram
    __shared__ double sred[8];                  // per-wave sse partials
    __shared__ int role_sh;                     // done-counter broadcast

    const int tid = threadIdx.x;
    const int lane = tid & 63, wv = tid >> 6;   // wv in [0,8)
    const int col = lane & 15, quad = lane >> 4;
    const int ntok0 = blockIdx.x * 256;

    wsqp[tid] = 1.25f;
    hist[tid] = 0;
    __syncthreads();  // B1: wsqp/hist init before use

    // ---- interleaved: 1 W-staging chunk + 4 X gather dwords per iter (8) ----
    const float* gbase = in + (ntok0 >> 12) * CHW + (ntok0 & 4095) + wv * 32 + col;
    short8 ah[2][2];
    float xsq = 0.f;
#pragma unroll
    for (int it = 0; it < 8; ++it) {
        const int g = it * 512 + tid;
        const int cc = g & 15, qd = (g >> 4) & 3, ch = (g >> 6) & 1, tt = g >> 7;
        const float4* src = (const float4*)(w + (tt * 16 + cc) * 64 + ch * 32 + qd * 8);
        const float4 v0 = src[0], v1 = src[1];
        const int sub = it >> 2, c = (it >> 1) & 1, j0 = (it & 1) * 4;
        const float* gp = gbase + sub * 16 + (c * 32 + quad * 8 + j0) * HW;
        const float x0 = gp[0 * HW], x1 = gp[1 * HW], x2 = gp[2 * HW], x3 = gp[3 * HW];

        short8 hv;
        hv[0] = (short)f2bf(v0.x); hv[1] = (short)f2bf(v0.y);
        hv[2] = (short)f2bf(v0.z); hv[3] = (short)f2bf(v0.w);
        hv[4] = (short)f2bf(v1.x); hv[5] = (short)f2bf(v1.y);
        hv[6] = (short)f2bf(v1.z); hv[7] = (short)f2bf(v1.w);
        *(short8*)(wh + g * 8) = hv;
        float ws2 = v0.x * v0.x;
        ws2 = fmaf(v0.y, v0.y, ws2); ws2 = fmaf(v0.z, v0.z, ws2);
        ws2 = fmaf(v0.w, v0.w, ws2); ws2 = fmaf(v1.x, v1.x, ws2);
        ws2 = fmaf(v1.y, v1.y, ws2); ws2 = fmaf(v1.z, v1.z, ws2);
        ws2 = fmaf(v1.w, v1.w, ws2);
        atomicAdd(&wsqp[tt * 16 + cc], ws2);  // LDS atomic

        ah[sub][c][j0 + 0] = (short)f2bf(-2.0f * x0);
        ah[sub][c][j0 + 1] = (short)f2bf(-2.0f * x1);
        ah[sub][c][j0 + 2] = (short)f2bf(-2.0f * x2);
        ah[sub][c][j0 + 3] = (short)f2bf(-2.0f * x3);
        xsq = fmaf(x0, x0, xsq); xsq = fmaf(x1, x1, xsq);
        xsq = fmaf(x2, x2, xsq); xsq = fmaf(x3, x3, xsq);
    }
    __syncthreads();  // B2: wh + wsqp complete

    // ---- scan 32 tiles of 16 codes; key = (float_bits(d)<<9)|code ----
    unsigned runkey[2][4];
#pragma unroll
    for (int sub = 0; sub < 2; ++sub)
#pragma unroll
        for (int r = 0; r < 4; ++r) runkey[sub][r] = 0xFFFFFFFFu;

#pragma unroll 1
    for (int t = 0; t < 32; ++t) {
        const unsigned short* ph = wh + t * 1024 + quad * 128 + col * 8;
        const short8 b0 = *(const short8*)ph;
        const short8 b1 = *(const short8*)(ph + 512);
        const int code = t * 16 + col;
        const float seed = wsqp[code];
#pragma unroll
        for (int sub = 0; sub < 2; ++sub) {
            f32x4 acc = {seed, seed, seed, seed};
            acc = __builtin_amdgcn_mfma_f32_16x16x32_bf16(ah[sub][0], b0, acc, 0, 0, 0);
            acc = __builtin_amdgcn_mfma_f32_16x16x32_bf16(ah[sub][1], b1, acc, 0, 0, 0);
#pragma unroll
            for (int r = 0; r < 4; ++r) {
                const unsigned key = (__float_as_uint(acc[r]) << 9) | code;
                runkey[sub][r] = key < runkey[sub][r] ? key : runkey[sub][r];
            }
        }
    }

    // ---- cross-lane argmin over the 16 code-cols ----
#pragma unroll
    for (int s = 1; s < 16; s <<= 1)
#pragma unroll
        for (int sub = 0; sub < 2; ++sub)
#pragma unroll
            for (int r = 0; r < 4; ++r) {
                const unsigned o = __shfl_xor(runkey[sub][r], s, 64);
                runkey[sub][r] = o < runkey[sub][r] ? o : runkey[sub][r];
            }

    // d_best (exact from key) + publish indices (wave-local consumers only)
    float dsum = 0.f;
    if (col == 0) {
#pragma unroll
        for (int sub = 0; sub < 2; ++sub)
#pragma unroll
            for (int r = 0; r < 4; ++r) {
                const unsigned key = runkey[sub][r];
                idxbuf[wv * 32 + sub * 16 + quad * 4 + r] = (int)(key & 511u);
                dsum += __uint_as_float((key >> 9) | 0x3F800000u) - 1.25f;
            }
    }
    float contrib = xsq + dsum;
#pragma unroll
    for (int off = 32; off > 0; off >>= 1) contrib += __shfl_down(contrib, off, 64);
    if (lane == 0) sred[wv] = (double)contrib;

    // per-wave histogram: idxbuf[wv*32+..] was written by THIS wave (col==0
    // lanes); wave-synchronous LDS RAW needs only compiler lgkmcnt — no B3.
    if (lane < 32) atomicAdd(&hist[idxbuf[wv * 32 + lane]], 1);

    // ---- epilogue: write w rows only (L2-hot); 4 lanes/token, 2 passes ----
    // plain cached stores: L2 write-combines the 16B/64B-stride pattern into
    // full lines (nontemporal here cost +43 MB HBM writes — R12 lesson).
#pragma unroll
    for (int p = 0; p < 2; ++p) {
        const int tl = p * 16 + (lane >> 2), q = lane & 3;
        const int n = ntok0 + wv * 32 + tl;
        const int bidx = idxbuf[wv * 32 + tl];
        const float4* wr = (const float4*)(w + bidx * 64 + q * 16);
        float4* op = (float4*)(out + n * 64 + q * 16);
#pragma unroll
        for (int i = 0; i < 4; ++i) op[i] = wr[i];
    }
    __syncthreads();  // B4: hist + sred complete

    if (!amode) {
        pcounts[(blockIdx.x << 9) + tid] = (float)hist[tid];  // plain store
        if (tid == 0) {
            double s = sred[0];
#pragma unroll
            for (int i = 1; i < 8; ++i) s += sred[i];
            ssep[blockIdx.x] = s;
        }
        __syncthreads();  // B5: all global stores issued (vmcnt drained)
        if (tid == 0) {
            __threadfence();                       // release: wb local L2
            role_sh = (int)atomicAdd(ctrs, 1u);    // device-scope
        }
        __syncthreads();  // B6: broadcast role
        const int old = role_sh;

        if (old >= 512 - 16) {  // one of the 16 last finishers -> reducer
            const int r = old - (512 - 16);
            if (tid == 0) {
                while (__hip_atomic_load(ctrs, __ATOMIC_RELAXED,
                                         __HIP_MEMORY_SCOPE_AGENT) < 512u)
                    __builtin_amdgcn_s_sleep(2);
            }
            __syncthreads();
            __threadfence();  // acquire: invalidate local caches

            // sum 32 pcounts rows for all 512 codes (coalesced across tid)
            const float* pc = pcounts + (r << 14) + tid;
            float s = 0.f;
#pragma unroll
            for (int b = 0; b < 32; ++b) s += pc[b << 9];  // integers: exact
            part2[(r << 9) + tid] = s;
            __syncthreads();  // drain partial stores
            if (tid == 0) {
                __threadfence();
                role_sh = (int)atomicAdd(ctrs + 1, 1u);
            }
            __syncthreads();

            if (role_sh == 15) {  // last reducer -> combiner (no spin needed)
                __threadfence();
                // wh is dead past the scan: reuse as double scratch
                double* const dred = (double*)wh;
                double* const dsred = dred + KCODES;
                float cnt = 0.f;
#pragma unroll
                for (int rr = 0; rr < 16; ++rr) cnt += part2[(rr << 9) + tid];
                const double p = (double)cnt / (double)NTOK;
                dred[tid] = p * log(p + 1e-10);
                dsred[tid] = ssep[tid];
                __syncthreads();
#pragma unroll
                for (int st = 256; st > 0; st >>= 1) {
                    if (tid < st) {
                        dred[tid] += dred[tid + st];
                        dsred[tid] += dsred[tid + st];
                    }
                    __syncthreads();
                }
                if (tid == 0) {
                    out[NELEM] = (float)((dsred[0] / (double)NELEM) * 1.25);
                    out[NELEM + 1] = (float)exp(-dred[0]);
                }
            }
        }
    } else {  // fallback: ws too small for partials/counters
        const int h = hist[tid];
        if (h) atomicAdd(&counts[tid], (float)h);
        if (tid == 0) {
            double s = sred[0];
#pragma unroll
            for (int i = 1; i < 8; ++i) s += sred[i];
            atomicAdd(sse_acc, s);
        }
    }
}

__global__ __launch_bounds__(512) void vq_final_a(const float* __restrict__ counts,
                                                  const double* __restrict__ sse_acc,
                                                  float* __restrict__ out) {
    __shared__ double red[512];
    const int k = threadIdx.x;
    const double p = (double)counts[k] / (double)NTOK;
    red[k] = p * log(p + 1e-10);
    __syncthreads();
#pragma unroll
    for (int st = 256; st > 0; st >>= 1) {
        if (k < st) red[k] += red[k + st];
        __syncthreads();
    }
    if (k == 0) {
        out[NELEM] = (float)((*sse_acc / (double)NELEM) * 1.25);
        out[NELEM + 1] = (float)exp(-red[0]);
    }
}

extern "C" void kernel_launch(void* const* d_in, const int* in_sizes, int n_in,
                              void* d_out, int out_size, void* d_ws, size_t ws_size,
                              hipStream_t stream) {
    const float* in = (const float*)d_in[0];
    const float* w = (const float*)d_in[1];
    float* out = (float*)d_out;
    char* ws = (char*)d_ws;

    const size_t PC = 0;
    const size_t SS = (size_t)1 << 20;            // 1 MB
    const size_t P2 = SS + 4096;                  // +4 KB
    const size_t CT = P2 + 32768;                 // +32 KB
    const size_t need = CT + 8;
    if (ws_size >= need) {
        float* pcounts = (float*)(ws + PC);
        double* ssep = (double*)(ws + SS);
        float* part2 = (float*)(ws + P2);
        unsigned* ctrs = (unsigned*)(ws + CT);
        (void)hipMemsetAsync(ctrs, 0, 8, stream); // zero done-counters (8 B)
        vq_main<<<512, 512, 0, stream>>>(in, w, out, pcounts, ssep, part2, ctrs,
                                         nullptr, nullptr, 0);
    } else {  // fallback: R6-style atomics
        float* counts = (float*)ws;
        double* sse_acc = (double*)(ws + 2048);
        (void)hipMemsetAsync(ws, 0, 2056, stream);
        vq_main<<<512, 512, 0, stream>>>(in, w, out, nullptr, nullptr, nullptr,
                                         nullptr, counts, sse_acc, 1);
        vq_final_a<<<1, 512, 0, stream>>>(counts, sse_acc, out);
    }
}

// Round 4
// 113.390 us; speedup vs baseline: 1.5178x; 1.2392x over previous
//
#include <hip/hip_runtime.h>
#include <math.h>

// VectorQuantizer on MI355X — R14: revert cascade (R12/R13 lesson: per-block
// device-scope fences cost ~40 µs — buffer_wbl2+inv per block on XCD-
// noncoherent L2s; same magnitude as R9's global-atomic removal 79.5->43.6).
// Back to the R10 two-kernel structure. Two isolated, per-dispatch-attributable
// changes vs R10:
//  1. vq_main phase-1 LOAD HOIST: VGPR=52 showed the compiler kept only ~6
//     loads in flight; issue all 32 X-gather dwords first (longest latency),
//     then W float4s in 2 halves, process W under X cover, then pack X.
//     ~48 load instrs in flight, ~90-120 VGPR (<=128 keeps 2 blocks/CU).
//  2. pcounts as ushort [512][512] = 512 KB: halves vq_final_p's single-CU
//     pull. hist <= 256 fits; count sums integer-exact in f32.
// Kept from R12/R13 (strictly-less-work): B3 removal + per-wave histogram.
// ws: [0,512K) pcounts u16[512][512] | [512K,+4K) ssep f64[512]

#define NTOK 131072
#define KCODES 512
#define HW 4096
#define CHW 262144
#define NELEM 8388608

typedef __attribute__((ext_vector_type(8))) short short8;
typedef __attribute__((ext_vector_type(4))) float f32x4;
typedef __attribute__((ext_vector_type(4))) unsigned short u16x4;

static __device__ __forceinline__ unsigned short f2bf(float f) {
    unsigned u = __float_as_uint(f);
    unsigned r = u + 0x7FFFu + ((u >> 16) & 1u);  // RNE
    return (unsigned short)(r >> 16);
}

__global__ __launch_bounds__(512, 4) void vq_main(const float* __restrict__ in,
                                                  const float* __restrict__ w,
                                                  float* __restrict__ out,
                                                  unsigned short* __restrict__ pcounts,
                                                  double* __restrict__ ssep,
                                                  float* __restrict__ counts,
                                                  double* __restrict__ sse_acc,
                                                  const int amode) {
    __shared__ __align__(16) unsigned short wh[KCODES * 64];  // 65536 B bf16 W
    __shared__ float wsqp[KCODES];              // 2048 B: 1.25 + ||w_k||^2
    __shared__ int idxbuf[256];                 // 1024 B
    __shared__ int hist[KCODES];                // 2048 B block histogram
    __shared__ double sred[8];                  // per-wave sse partials

    const int tid = threadIdx.x;
    const int lane = tid & 63, wv = tid >> 6;   // wv in [0,8)
    const int col = lane & 15, quad = lane >> 4;
    const int ntok0 = blockIdx.x * 256;

    wsqp[tid] = 1.25f;
    hist[tid] = 0;
    __syncthreads();  // B1: wsqp/hist init before use

    // ---- phase 1: hoisted loads ----
    // X gather: 32 dwords/thread at HW stride (HBM/L3 latency) — issue ALL
    // first. W: 8 float4-pairs (L2-hot) in 2 halves; W processing covers X.
    const float* gbase = in + (ntok0 >> 12) * CHW + (ntok0 & 4095) + wv * 32 + col;
    const float4* wsrc = (const float4*)(w + ((tid >> 7) * 16 + (tid & 15)) * 64
                                           + ((tid >> 6) & 1) * 32
                                           + ((tid >> 4) & 3) * 8);
    float xv[8][4];
#pragma unroll
    for (int it = 0; it < 8; ++it) {
        const int sub = it >> 2, c = (it >> 1) & 1, j0 = (it & 1) * 4;
        const float* gp = gbase + sub * 16 + (c * 32 + quad * 8 + j0) * HW;
        xv[it][0] = gp[0 * HW]; xv[it][1] = gp[1 * HW];
        xv[it][2] = gp[2 * HW]; xv[it][3] = gp[3 * HW];
    }

#pragma unroll
    for (int h = 0; h < 2; ++h) {
        float4 wv0[4], wv1[4];
#pragma unroll
        for (int i = 0; i < 4; ++i) {
            wv0[i] = wsrc[(h * 4 + i) * 1024];
            wv1[i] = wsrc[(h * 4 + i) * 1024 + 1];
        }
#pragma unroll
        for (int i = 0; i < 4; ++i) {
            const int g = (h * 4 + i) * 512 + tid;
            short8 hv;
            hv[0] = (short)f2bf(wv0[i].x); hv[1] = (short)f2bf(wv0[i].y);
            hv[2] = (short)f2bf(wv0[i].z); hv[3] = (short)f2bf(wv0[i].w);
            hv[4] = (short)f2bf(wv1[i].x); hv[5] = (short)f2bf(wv1[i].y);
            hv[6] = (short)f2bf(wv1[i].z); hv[7] = (short)f2bf(wv1[i].w);
            *(short8*)(wh + g * 8) = hv;
            float ws2 = wv0[i].x * wv0[i].x;
            ws2 = fmaf(wv0[i].y, wv0[i].y, ws2); ws2 = fmaf(wv0[i].z, wv0[i].z, ws2);
            ws2 = fmaf(wv0[i].w, wv0[i].w, ws2); ws2 = fmaf(wv1[i].x, wv1[i].x, ws2);
            ws2 = fmaf(wv1[i].y, wv1[i].y, ws2); ws2 = fmaf(wv1[i].z, wv1[i].z, ws2);
            ws2 = fmaf(wv1[i].w, wv1[i].w, ws2);
            atomicAdd(&wsqp[(g >> 7) * 16 + (g & 15)], ws2);  // LDS atomic
        }
    }

    short8 ah[2][2];
    float xsq = 0.f;
#pragma unroll
    for (int it = 0; it < 8; ++it) {
        const int sub = it >> 2, c = (it >> 1) & 1, j0 = (it & 1) * 4;
        ah[sub][c][j0 + 0] = (short)f2bf(-2.0f * xv[it][0]);
        ah[sub][c][j0 + 1] = (short)f2bf(-2.0f * xv[it][1]);
        ah[sub][c][j0 + 2] = (short)f2bf(-2.0f * xv[it][2]);
        ah[sub][c][j0 + 3] = (short)f2bf(-2.0f * xv[it][3]);
        xsq = fmaf(xv[it][0], xv[it][0], xsq); xsq = fmaf(xv[it][1], xv[it][1], xsq);
        xsq = fmaf(xv[it][2], xv[it][2], xsq); xsq = fmaf(xv[it][3], xv[it][3], xsq);
    }
    __syncthreads();  // B2: wh + wsqp complete

    // ---- scan 32 tiles of 16 codes; key = (float_bits(d)<<9)|code ----
    unsigned runkey[2][4];
#pragma unroll
    for (int sub = 0; sub < 2; ++sub)
#pragma unroll
        for (int r = 0; r < 4; ++r) runkey[sub][r] = 0xFFFFFFFFu;

#pragma unroll 1
    for (int t = 0; t < 32; ++t) {
        const unsigned short* ph = wh + t * 1024 + quad * 128 + col * 8;
        const short8 b0 = *(const short8*)ph;
        const short8 b1 = *(const short8*)(ph + 512);
        const int code = t * 16 + col;
        const float seed = wsqp[code];
#pragma unroll
        for (int sub = 0; sub < 2; ++sub) {
            f32x4 acc = {seed, seed, seed, seed};
            acc = __builtin_amdgcn_mfma_f32_16x16x32_bf16(ah[sub][0], b0, acc, 0, 0, 0);
            acc = __builtin_amdgcn_mfma_f32_16x16x32_bf16(ah[sub][1], b1, acc, 0, 0, 0);
#pragma unroll
            for (int r = 0; r < 4; ++r) {
                const unsigned key = (__float_as_uint(acc[r]) << 9) | code;
                runkey[sub][r] = key < runkey[sub][r] ? key : runkey[sub][r];
            }
        }
    }

    // ---- cross-lane argmin over the 16 code-cols ----
#pragma unroll
    for (int s = 1; s < 16; s <<= 1)
#pragma unroll
        for (int sub = 0; sub < 2; ++sub)
#pragma unroll
            for (int r = 0; r < 4; ++r) {
                const unsigned o = __shfl_xor(runkey[sub][r], s, 64);
                runkey[sub][r] = o < runkey[sub][r] ? o : runkey[sub][r];
            }

    // d_best (exact from key) + publish indices (wave-local consumers only)
    float dsum = 0.f;
    if (col == 0) {
#pragma unroll
        for (int sub = 0; sub < 2; ++sub)
#pragma unroll
            for (int r = 0; r < 4; ++r) {
                const unsigned key = runkey[sub][r];
                idxbuf[wv * 32 + sub * 16 + quad * 4 + r] = (int)(key & 511u);
                dsum += __uint_as_float((key >> 9) | 0x3F800000u) - 1.25f;
            }
    }
    float contrib = xsq + dsum;
#pragma unroll
    for (int off = 32; off > 0; off >>= 1) contrib += __shfl_down(contrib, off, 64);
    if (lane == 0) sred[wv] = (double)contrib;

    // per-wave histogram: idxbuf[wv*32+..] was written by THIS wave (col==0
    // lanes); wave-synchronous LDS RAW needs only compiler lgkmcnt — no B3.
    if (lane < 32) atomicAdd(&hist[idxbuf[wv * 32 + lane]], 1);

    // ---- epilogue: write w rows only (L2-hot); 4 lanes/token, 2 passes ----
    // plain cached stores: L2 write-combines the 16B/64B-stride pattern
    // (nontemporal here cost +43 MB HBM writes — R12 lesson).
#pragma unroll
    for (int p = 0; p < 2; ++p) {
        const int tl = p * 16 + (lane >> 2), q = lane & 3;
        const int n = ntok0 + wv * 32 + tl;
        const int bidx = idxbuf[wv * 32 + tl];
        const float4* wr = (const float4*)(w + bidx * 64 + q * 16);
        float4* op = (float4*)(out + n * 64 + q * 16);
#pragma unroll
        for (int i = 0; i < 4; ++i) op[i] = wr[i];
    }
    __syncthreads();  // B4: hist + sred complete

    if (!amode) {
        pcounts[(blockIdx.x << 9) + tid] = (unsigned short)hist[tid];
        if (tid == 0) {
            double s = sred[0];
#pragma unroll
            for (int i = 1; i < 8; ++i) s += sred[i];
            ssep[blockIdx.x] = s;
        }
    } else {  // fallback: ws too small for partials
        const int h = hist[tid];
        if (h) atomicAdd(&counts[tid], (float)h);
        if (tid == 0) {
            double s = sred[0];
#pragma unroll
            for (int i = 1; i < 8; ++i) s += sred[i];
            atomicAdd(sse_acc, s);
        }
    }
}

// parallel reduce: thread t owns 4 codes x 1 block-quarter; u16x4 coalesced
__global__ __launch_bounds__(512) void vq_final_p(const unsigned short* __restrict__ pcounts,
                                                  const double* __restrict__ ssep,
                                                  float* __restrict__ out) {
    __shared__ float part[4][512];   // 8 KB: quarter x code
    __shared__ double red[512];
    __shared__ double sred[512];
    const int t = threadIdx.x;
    const int q = t >> 7, c4 = (t & 127) << 2;

    const u16x4* base = (const u16x4*)pcounts + (q << 14) + (c4 >> 2);
    float4 s = {0.f, 0.f, 0.f, 0.f};
#pragma unroll 16
    for (int b = 0; b < 128; ++b) {        // rows q*128 .. q*128+128
        const u16x4 v = base[b << 7];      // stride 512 ushorts = 128 u16x4
        s.x += (float)v[0]; s.y += (float)v[1];
        s.z += (float)v[2]; s.w += (float)v[3];
    }
    *(float4*)&part[q][c4] = s;
    sred[t] = ssep[t];
    __syncthreads();

    const float cnt = part[0][t] + part[1][t] + part[2][t] + part[3][t];
    const double p = (double)cnt / (double)NTOK;
    red[t] = p * log(p + 1e-10);
    __syncthreads();
#pragma unroll
    for (int st = 256; st > 0; st >>= 1) {
        if (t < st) { red[t] += red[t + st]; sred[t] += sred[t + st]; }
        __syncthreads();
    }
    if (t == 0) {
        out[NELEM] = (float)((sred[0] / (double)NELEM) * 1.25);
        out[NELEM + 1] = (float)exp(-red[0]);
    }
}

__global__ __launch_bounds__(512) void vq_final_a(const float* __restrict__ counts,
                                                  const double* __restrict__ sse_acc,
                                                  float* __restrict__ out) {
    __shared__ double red[512];
    const int k = threadIdx.x;
    const double p = (double)counts[k] / (double)NTOK;
    red[k] = p * log(p + 1e-10);
    __syncthreads();
#pragma unroll
    for (int st = 256; st > 0; st >>= 1) {
        if (k < st) red[k] += red[k + st];
        __syncthreads();
    }
    if (k == 0) {
        out[NELEM] = (float)((*sse_acc / (double)NELEM) * 1.25);
        out[NELEM + 1] = (float)exp(-red[0]);
    }
}

extern "C" void kernel_launch(void* const* d_in, const int* in_sizes, int n_in,
                              void* d_out, int out_size, void* d_ws, size_t ws_size,
                              hipStream_t stream) {
    const float* in = (const float*)d_in[0];
    const float* w = (const float*)d_in[1];
    float* out = (float*)d_out;
    char* ws = (char*)d_ws;

    const size_t SS = (size_t)512 * 512 * 2;      // 512 KB of ushort partials
    const size_t need = SS + 512 * 8;             // + ssep f64[512]
    if (ws_size >= need) {
        unsigned short* pcounts = (unsigned short*)ws;
        double* ssep = (double*)(ws + SS);
        vq_main<<<512, 512, 0, stream>>>(in, w, out, pcounts, ssep,
                                         nullptr, nullptr, 0);
        vq_final_p<<<1, 512, 0, stream>>>(pcounts, ssep, out);
    } else {  // fallback: R6-style atomics
        float* counts = (float*)ws;
        double* sse_acc = (double*)(ws + 2048);
        (void)hipMemsetAsync(ws, 0, 2056, stream);
        vq_main<<<512, 512, 0, stream>>>(in, w, out, nullptr, nullptr,
                                         counts, sse_acc, 1);
        vq_final_a<<<1, 512, 0, stream>>>(counts, sse_acc, out);
    }
}